// Round 9
// baseline (1281.541 us; speedup 1.0000x reference)
//
#include <hip/hip_runtime.h>

#define N_NODES 50000
#define S_NEI 16
#define E_EDGES 400000
#define DDIM 128
#define EDIMC 64
#define NMPC 2
#define DEPTHC 2

typedef __attribute__((ext_vector_type(8))) short short8v;
typedef __attribute__((ext_vector_type(4))) float float4v;

__device__ __forceinline__ unsigned short f2bf(float f) {
  unsigned int u = __float_as_uint(f);
  unsigned int r = (u + 0x7fffu + ((u >> 16) & 1u)) >> 16;
  return (unsigned short)r;
}
__device__ __forceinline__ float bf2f(unsigned short h) { return __uint_as_float((unsigned int)h << 16); }
__device__ __forceinline__ float bflo(unsigned int u) { return __uint_as_float(u << 16); }
__device__ __forceinline__ float bfhi(unsigned int u) { return __uint_as_float(u & 0xffff0000u); }

// ---------------------------------------------------------------------------
// Weight table: 27 slots x 16384 bf16.
//  slots ml*6 + {0:k_e, 1:v_e, 2:q_n, 3:q_e, 4:k_n, 5:v_n}  (ml = mp*2+l), each [c=128][d=128]
//  slot 24: Wprep^T [c=128][d=128]; slots 25,26: Wedgeprep[mp]^T [c=128][k=64] zero-padded
// ---------------------------------------------------------------------------
__global__ void build_wt(const float* __restrict__ Wprep, const float* __restrict__ Wedgeprep,
                         const float* __restrict__ Wq_e, const float* __restrict__ Wk_e,
                         const float* __restrict__ Wv_e, const float* __restrict__ Wq_n,
                         const float* __restrict__ Wk_n, const float* __restrict__ Wv_n,
                         unsigned short* __restrict__ WT) {
  int idx = blockIdx.x * 256 + threadIdx.x;
  if (idx >= 27 * 16384) return;
  int slot = idx >> 14, r = idx & 16383;
  float v = 0.f;
  if (slot < 24) {
    int ml = slot / 6, mat = slot % 6;
    int c = r >> 7, d = r & 127;
    int h = c >> 5, kk = c & 31;
    const float* W = (mat == 0) ? Wk_e : (mat == 1) ? Wv_e : (mat == 2) ? Wq_n
                   : (mat == 3) ? Wq_e : (mat == 4) ? Wk_n : Wv_n;
    v = W[(((size_t)ml * 4 + h) * 128 + d) * 32 + kk];
  } else if (slot == 24) {
    int c = r >> 7, d = r & 127;
    v = Wprep[d * 128 + c];
  } else {
    int mp = slot - 25;
    int c = r >> 6, k = r & 63;
    if (c < 128) v = Wedgeprep[((size_t)mp * 64 + k) * 128 + c];
  }
  WT[idx] = f2bf(v);
}

// ---------------------------------------------------------------------------
// proj: Y_w[m][c] = bf16( X[m][:] @ W_w ), per-output row stride rs_w (u16 units)
// ---------------------------------------------------------------------------
template<int KDIM, int NW, bool ASPLIT>
__global__ __launch_bounds__(256, 3)
void proj(const unsigned short* __restrict__ Xbf, const float* __restrict__ Xf,
          const unsigned short* __restrict__ WT,
          unsigned short* __restrict__ Y0, unsigned short* __restrict__ Y1,
          unsigned short* __restrict__ Y2, int rs0, int rs1, int rs2, int M) {
  constexpr int NKK  = KDIM / 32;
  constexpr int CHPR = KDIM / 8;
  constexpr int SWZ  = CHPR - 1;
  __shared__ unsigned short Wl[128 * KDIM];
  const int tid  = threadIdx.x;
  const int lane = tid & 63;
  const int wv   = tid >> 6;
  const int l15  = lane & 15, lg = lane >> 4;
  const long m0  = (long)blockIdx.x * 128 + wv * 32;

  short8v xb[2][NKK];
  #pragma unroll
  for (int rf = 0; rf < 2; ++rf) {
    long row = m0 + rf * 16 + l15; if (row >= M) row = M - 1;
    #pragma unroll
    for (int kk = 0; kk < NKK; ++kk) {
      const int k0 = kk * 32 + lg * 8;
      if (ASPLIT) {
        const float* p = Xf + row * KDIM + k0;
        float4v a0 = *(const float4v*)p;
        float4v a1 = *(const float4v*)(p + 4);
        #pragma unroll
        for (int j = 0; j < 8; ++j) {
          float x = (j < 4) ? a0[j] : a1[j - 4];
          xb[rf][kk][j] = (short)f2bf(x);
        }
      } else {
        xb[rf][kk] = *(const short8v*)(Xbf + row * KDIM + k0);
      }
    }
  }

  unsigned short* Ys[3] = {Y0, Y1, Y2};
  const int rsv[3] = {rs0, rs1, rs2};
  #pragma unroll
  for (int w = 0; w < NW; ++w) {
    if (w) __syncthreads();
    {
      const uint4* src = (const uint4*)(WT + (size_t)w * 16384);
      #pragma unroll
      for (int i = 0; i < CHPR / 2; ++i) {
        int ci = i * 256 + tid;
        int row = ci / CHPR, ch = ci & SWZ;
        uint4 v = src[ci];
        *(uint4*)((char*)Wl + row * (KDIM * 2) + ((ch ^ (row & SWZ)) << 4)) = v;
      }
    }
    __syncthreads();

    float4v acc[8][2];
    #pragma unroll
    for (int cf = 0; cf < 8; ++cf)
      #pragma unroll
      for (int rf = 0; rf < 2; ++rf) acc[cf][rf] = (float4v)0.f;

    #pragma unroll
    for (int kk = 0; kk < NKK; ++kk) {
      #pragma unroll
      for (int cf = 0; cf < 8; ++cf) {
        const int row = cf * 16 + l15;
        const int ch  = (kk * 4 + lg) ^ (row & SWZ);
        short8v b = *(const short8v*)((char*)Wl + row * (KDIM * 2) + (ch << 4));
        acc[cf][0] = __builtin_amdgcn_mfma_f32_16x16x32_bf16(b, xb[0][kk], acc[cf][0], 0, 0, 0);
        acc[cf][1] = __builtin_amdgcn_mfma_f32_16x16x32_bf16(b, xb[1][kk], acc[cf][1], 0, 0, 0);
      }
    }

    #pragma unroll
    for (int rf = 0; rf < 2; ++rf) {
      const long m = m0 + rf * 16 + l15;
      if (m < M) {
        #pragma unroll
        for (int cf = 0; cf < 8; ++cf) {
          const int c0 = cf * 16 + lg * 4;
          float4v a = acc[cf][rf];
          ushort4 o;
          o.x = f2bf(a[0]); o.y = f2bf(a[1]); o.z = f2bf(a[2]); o.w = f2bf(a[3]);
          *(ushort4*)(Ys[w] + m * (long)rsv[w] + c0) = o;
        }
      }
    }
  }
}

// ---------------------------------------------------------------------------
// edge_fused<PREP>: per 128-edge tile. All dense global accesses go through an
// LDS transpose (Wl reused sequentially) so they are fully coalesced:
//  - state read: contiguous 32KB block -> LDS (XOR-swz) -> fragment ds_reads
//  - K/V phases: MFMA -> acc dumped bf16 to LDS -> coalesced 256B-row stores
//  - tail: output dumped to LDS -> one contiguous 32KB store
// PREP (layer 0): state built from emb @ Wedgeprep via MFMA instead of read.
// E divisible by 128; no guards.
// ---------------------------------------------------------------------------
template<int PREP>
__global__ __launch_bounds__(256, 3)
void edge_fused(unsigned short* __restrict__ ehi, const unsigned short* __restrict__ WTqe,
                const unsigned short* __restrict__ KVn, const int* __restrict__ adj,
                unsigned short* __restrict__ KVe,
                const float* __restrict__ emb, const unsigned short* __restrict__ WTprep) {
  __shared__ unsigned short Wl[128 * 128];
  const int tid  = threadIdx.x;
  const int lane = tid & 63;
  const int wv   = tid >> 6;
  const int l15  = lane & 15, lg = lane >> 4;
  const long m0  = (long)blockIdx.x * 128 + wv * 32;

  short8v xb[2][4];
  if (PREP) {
    // ---- stage Wedgeprep^T [c=128][k=64] bf16 = 16KB (8 chunks/row, SWZ=7) ----
    {
      const uint4* src = (const uint4*)WTprep;
      #pragma unroll
      for (int i = 0; i < 4; ++i) {
        int ci = i * 256 + tid;
        int row = ci >> 3, ch = ci & 7;
        uint4 v = src[ci];
        *(uint4*)((char*)Wl + row * 128 + ((ch ^ (row & 7)) << 4)) = v;
      }
    }
    // ---- emb fragments (f32 -> bf16), KDIM=64 ----
    short8v eb[2][2];
    #pragma unroll
    for (int rf = 0; rf < 2; ++rf) {
      const long row = m0 + rf * 16 + l15;
      #pragma unroll
      for (int kk = 0; kk < 2; ++kk) {
        const float* p = emb + row * 64 + kk * 32 + lg * 8;
        float4v a0 = *(const float4v*)p;
        float4v a1 = *(const float4v*)(p + 4);
        #pragma unroll
        for (int j = 0; j < 8; ++j) {
          float x = (j < 4) ? a0[j] : a1[j - 4];
          eb[rf][kk][j] = (short)f2bf(x);
        }
      }
    }
    __syncthreads();
    float4v accP[8][2];
    #pragma unroll
    for (int cf = 0; cf < 8; ++cf)
      #pragma unroll
      for (int rf = 0; rf < 2; ++rf) accP[cf][rf] = (float4v)0.f;
    #pragma unroll
    for (int kk = 0; kk < 2; ++kk) {
      #pragma unroll
      for (int cf = 0; cf < 8; ++cf) {
        const int row = cf * 16 + l15;
        const int ch  = (kk * 4 + lg) ^ (row & 7);
        short8v b = *(const short8v*)((char*)Wl + row * 128 + (ch << 4));
        accP[cf][0] = __builtin_amdgcn_mfma_f32_16x16x32_bf16(b, eb[0][kk], accP[cf][0], 0, 0, 0);
        accP[cf][1] = __builtin_amdgcn_mfma_f32_16x16x32_bf16(b, eb[1][kk], accP[cf][1], 0, 0, 0);
      }
    }
    __syncthreads();  // all W reads done before overwrite
    // ---- dump state bf16 -> LDS [er=128][c=128], 16B-chunk XOR swizzle ----
    #pragma unroll
    for (int rf = 0; rf < 2; ++rf) {
      const int er = wv * 32 + rf * 16 + l15;
      #pragma unroll
      for (int cf = 0; cf < 8; ++cf) {
        float4v a = accP[cf][rf];
        ushort4 o;
        o.x = f2bf(a[0]); o.y = f2bf(a[1]); o.z = f2bf(a[2]); o.w = f2bf(a[3]);
        const int ch16 = cf * 2 + (lg >> 1);
        const int off  = er * 256 + ((ch16 ^ (er & 15)) << 4) + (lg & 1) * 8;
        *(ushort4*)((char*)Wl + off) = o;
      }
    }
    __syncthreads();
    // ---- read back as B-fragments ----
    #pragma unroll
    for (int rf = 0; rf < 2; ++rf) {
      const int row = wv * 32 + rf * 16 + l15;
      #pragma unroll
      for (int kk = 0; kk < 4; ++kk) {
        const int ch = (kk * 4 + lg) ^ (row & 15);
        xb[rf][kk] = *(const short8v*)((char*)Wl + row * 256 + (ch << 4));
      }
    }
  } else {
    // ---- state read: contiguous 32KB -> LDS (swz) -> fragments ----
    {
      const uint4* src = (const uint4*)(ehi + (size_t)blockIdx.x * 16384);
      #pragma unroll
      for (int i = 0; i < 8; ++i) {
        int c = i * 256 + tid;            // 16B-chunk index, 2048 total
        int row = c >> 4, ch = c & 15;
        uint4 v = src[c];
        *(uint4*)((char*)Wl + row * 256 + ((ch ^ (row & 15)) << 4)) = v;
      }
    }
    __syncthreads();
    #pragma unroll
    for (int rf = 0; rf < 2; ++rf) {
      const int row = wv * 32 + rf * 16 + l15;
      #pragma unroll
      for (int kk = 0; kk < 4; ++kk) {
        const int ch = (kk * 4 + lg) ^ (row & 15);
        xb[rf][kk] = *(const short8v*)((char*)Wl + row * 256 + (ch << 4));
      }
    }
  }

  float4v accQ[8][2];
  // phase 0: k_n (slot 1), phase 1: v_n (slot 2), phase 2: q_e (slot 0)
  const int slot_of[3] = {1, 2, 0};
  #pragma unroll
  for (int ph = 0; ph < 3; ++ph) {
    __syncthreads();   // previous Wl reads (frags / store-reads) done
    {
      const uint4* src = (const uint4*)(WTqe + (size_t)slot_of[ph] * 16384);
      #pragma unroll
      for (int i = 0; i < 8; ++i) {
        int ci = i * 256 + tid;
        int row = ci >> 4, ch = ci & 15;
        uint4 v = src[ci];
        *(uint4*)((char*)Wl + row * 256 + ((ch ^ (row & 15)) << 4)) = v;
      }
    }
    __syncthreads();

    float4v acc[8][2];
    #pragma unroll
    for (int cf = 0; cf < 8; ++cf)
      #pragma unroll
      for (int rf = 0; rf < 2; ++rf) acc[cf][rf] = (float4v)0.f;

    #pragma unroll
    for (int kk = 0; kk < 4; ++kk) {
      #pragma unroll
      for (int cf = 0; cf < 8; ++cf) {
        const int row = cf * 16 + l15;
        const int ch  = (kk * 4 + lg) ^ (row & 15);
        short8v b = *(const short8v*)((char*)Wl + row * 256 + (ch << 4));
        acc[cf][0] = __builtin_amdgcn_mfma_f32_16x16x32_bf16(b, xb[0][kk], acc[cf][0], 0, 0, 0);
        acc[cf][1] = __builtin_amdgcn_mfma_f32_16x16x32_bf16(b, xb[1][kk], acc[cf][1], 0, 0, 0);
      }
    }

    if (ph < 2) {
      __syncthreads();   // all W reads done before acc dump overwrites Wl
      #pragma unroll
      for (int rf = 0; rf < 2; ++rf) {
        const int er = wv * 32 + rf * 16 + l15;
        #pragma unroll
        for (int cf = 0; cf < 8; ++cf) {
          float4v a = acc[cf][rf];
          ushort4 o;
          o.x = f2bf(a[0]); o.y = f2bf(a[1]); o.z = f2bf(a[2]); o.w = f2bf(a[3]);
          const int ch16 = cf * 2 + (lg >> 1);
          const int off  = er * 256 + ((ch16 ^ (er & 15)) << 4) + (lg & 1) * 8;
          *(ushort4*)((char*)Wl + off) = o;
        }
      }
      __syncthreads();
      // coalesced store: KVe row = 512B, this phase's 256B half
      unsigned short* dst = KVe + (size_t)blockIdx.x * 32768 + ph * 128;
      #pragma unroll
      for (int i = 0; i < 8; ++i) {
        int c = i * 256 + tid;
        int row = c >> 4, ch = c & 15;
        uint4 v = *(const uint4*)((char*)Wl + row * 256 + ((ch ^ (row & 15)) << 4));
        *(uint4*)(dst + (size_t)row * 256 + ch * 8) = v;
      }
    } else {
      #pragma unroll
      for (int cf = 0; cf < 8; ++cf)
        #pragma unroll
        for (int rf = 0; rf < 2; ++rf) accQ[cf][rf] = acc[cf][rf];
    }
  }

  // ---- attention over 2 endpoints (fragment layout) ----
  const float scale = 0.17677669529663687f;  // 1/sqrt(32)
  ushort4 outv[2][8];
  #pragma unroll
  for (int rf = 0; rf < 2; ++rf) {
    const long e = m0 + rf * 16 + l15;
    const int2 nn = *(const int2*)(adj + e * 2);
    const size_t b0 = (size_t)nn.x * 256, b1 = (size_t)nn.y * 256;
    float p0[4] = {0.f, 0.f, 0.f, 0.f}, p1[4] = {0.f, 0.f, 0.f, 0.f};
    #pragma unroll
    for (int cf = 0; cf < 8; ++cf) {
      const int c0 = cf * 16 + lg * 4;
      const int h = cf >> 1;
      ushort4 k0 = *(const ushort4*)(KVn + b0 + c0);
      ushort4 k1 = *(const ushort4*)(KVn + b1 + c0);
      float4v q = accQ[cf][rf];
      p0[h] += q[0] * bf2f(k0.x) + q[1] * bf2f(k0.y) + q[2] * bf2f(k0.z) + q[3] * bf2f(k0.w);
      p1[h] += q[0] * bf2f(k1.x) + q[1] * bf2f(k1.y) + q[2] * bf2f(k1.z) + q[3] * bf2f(k1.w);
    }
    float a0[4], a1[4];
    #pragma unroll
    for (int h = 0; h < 4; ++h) {
      p0[h] += __shfl_xor(p0[h], 16); p0[h] += __shfl_xor(p0[h], 32);
      p1[h] += __shfl_xor(p1[h], 16); p1[h] += __shfl_xor(p1[h], 32);
      const float s0 = p0[h] * scale, s1 = p1[h] * scale;
      const float mx = fmaxf(s0, s1);
      const float e0 = __expf(s0 - mx), e1 = __expf(s1 - mx);
      const float inv = 1.0f / (e0 + e1);
      a0[h] = e0 * inv; a1[h] = e1 * inv;
    }
    #pragma unroll
    for (int cf = 0; cf < 8; ++cf) {
      const int c0 = cf * 16 + lg * 4;
      const int h = cf >> 1;
      ushort4 v0 = *(const ushort4*)(KVn + b0 + 128 + c0);
      ushort4 v1 = *(const ushort4*)(KVn + b1 + 128 + c0);
      float o[4];
      o[0] = a0[h] * bf2f(v0.x) + a1[h] * bf2f(v1.x);
      o[1] = a0[h] * bf2f(v0.y) + a1[h] * bf2f(v1.y);
      o[2] = a0[h] * bf2f(v0.z) + a1[h] * bf2f(v1.z);
      o[3] = a0[h] * bf2f(v0.w) + a1[h] * bf2f(v1.w);
      o[0] = o[0] > 0.f ? o[0] : expm1f(o[0]);
      o[1] = o[1] > 0.f ? o[1] : expm1f(o[1]);
      o[2] = o[2] > 0.f ? o[2] : expm1f(o[2]);
      o[3] = o[3] > 0.f ? o[3] : expm1f(o[3]);
      ushort4 ob;
      ob.x = f2bf(o[0]); ob.y = f2bf(o[1]); ob.z = f2bf(o[2]); ob.w = f2bf(o[3]);
      outv[rf][cf] = ob;
    }
  }
  // ---- output through LDS -> one contiguous 32KB store ----
  __syncthreads();   // all Q-phase Wl reads done (each wave past its MFMAs)
  #pragma unroll
  for (int rf = 0; rf < 2; ++rf) {
    const int er = wv * 32 + rf * 16 + l15;
    #pragma unroll
    for (int cf = 0; cf < 8; ++cf) {
      const int ch16 = cf * 2 + (lg >> 1);
      const int off  = er * 256 + ((ch16 ^ (er & 15)) << 4) + (lg & 1) * 8;
      *(ushort4*)((char*)Wl + off) = outv[rf][cf];
    }
  }
  __syncthreads();
  {
    unsigned short* dst = ehi + (size_t)blockIdx.x * 16384;
    #pragma unroll
    for (int i = 0; i < 8; ++i) {
      int c = i * 256 + tid;
      int row = c >> 4, ch = c & 15;
      uint4 v = *(const uint4*)((char*)Wl + row * 256 + ((ch ^ (row & 15)) << 4));
      *(uint4*)(dst + (size_t)c * 8) = v;
    }
  }
}

// ---------------------------------------------------------------------------
// node_attn: one wave per node, 16 incident edges, K/V gathered from
// interleaved KVe (512B per edge). Writes bf16 next-state + f32 output slice.
// ---------------------------------------------------------------------------
__global__ __launch_bounds__(256)
void node_attn(const unsigned int* __restrict__ Qn, const unsigned int* __restrict__ KVe,
               const int* __restrict__ n2e,
               unsigned short* __restrict__ fhi, float* __restrict__ outp) {
  const int lane = threadIdx.x & 63;
  const long n = (long)blockIdx.x * 4 + (threadIdx.x >> 6);
  const unsigned int q = Qn[n * 64 + lane];
  const float qa = bflo(q), qb = bfhi(q);
  float sc[16];
  unsigned int vv[16];
  #pragma unroll
  for (int s = 0; s < 16; ++s) {
    const long e = n2e[n * 16 + s];
    const unsigned int kk = KVe[e * 128 + lane];
    vv[s] = KVe[e * 128 + 64 + lane];
    float p = qa * bflo(kk) + qb * bfhi(kk);
    #pragma unroll
    for (int off = 1; off < 16; off <<= 1) p += __shfl_xor(p, off);
    sc[s] = p * 0.17677669529663687f;
  }
  float m = sc[0];
  #pragma unroll
  for (int s = 1; s < 16; ++s) m = fmaxf(m, sc[s]);
  float sum = 0.f;
  #pragma unroll
  for (int s = 0; s < 16; ++s) { sc[s] = __expf(sc[s] - m); sum += sc[s]; }
  const float inv = 1.0f / sum;
  float oa = 0.f, ob = 0.f;
  #pragma unroll
  for (int s = 0; s < 16; ++s) { oa += sc[s] * bflo(vv[s]); ob += sc[s] * bfhi(vv[s]); }
  oa *= inv; ob *= inv;
  oa = oa > 0.f ? oa : expm1f(oa);
  ob = ob > 0.f ? ob : expm1f(ob);
  ((unsigned int*)fhi)[n * 64 + lane] = (unsigned int)f2bf(oa) | ((unsigned int)f2bf(ob) << 16);
  *(float2*)(outp + n * 256 + lane * 2) = make_float2(oa, ob);
}

extern "C" void kernel_launch(void* const* d_in, const int* in_sizes, int n_in,
                              void* d_out, int out_size, void* d_ws, size_t ws_size,
                              hipStream_t stream) {
  const float* feats     = (const float*)d_in[0];
  const float* node_emb  = (const float*)d_in[1];
  const float* Wprep     = (const float*)d_in[2];
  const float* edge_emb  = (const float*)d_in[3];
  const float* Wedgeprep = (const float*)d_in[4];
  const float* Wq_e      = (const float*)d_in[5];
  const float* Wk_e      = (const float*)d_in[6];
  const float* Wv_e      = (const float*)d_in[7];
  const float* Wq_n      = (const float*)d_in[8];
  const float* Wk_n      = (const float*)d_in[9];
  const float* Wv_n      = (const float*)d_in[10];
  const int*   n2e       = (const int*)d_in[11];
  const int*   adj       = (const int*)d_in[12];
  float* out = (float*)d_out;

  char* w = (char*)d_ws;
  auto carve = [&](size_t bytes) -> char* {
    char* p = w; w += (bytes + 255) & ~(size_t)255; return p;
  };
  unsigned short* ehi   = (unsigned short*)carve((size_t)E_EDGES * 128 * 2);
  unsigned short* fprep = (unsigned short*)carve((size_t)N_NODES * 128 * 2);  // all_feats (both mp)
  unsigned short* fa    = (unsigned short*)carve((size_t)N_NODES * 128 * 2);
  unsigned short* fb    = (unsigned short*)carve((size_t)N_NODES * 128 * 2);
  unsigned short* KVe   = (unsigned short*)carve((size_t)E_EDGES * 256 * 2);  // interleaved K|V
  unsigned short* KVn   = (unsigned short*)carve((size_t)N_NODES * 256 * 2);  // interleaved K|V
  unsigned short* Qn    = (unsigned short*)carve((size_t)N_NODES * 128 * 2);
  unsigned short* WT    = (unsigned short*)carve((size_t)27 * 16384 * 2);

  build_wt<<<(27 * 16384 + 255) / 256, 256, 0, stream>>>(
      Wprep, Wedgeprep, Wq_e, Wk_e, Wv_e, Wq_n, Wk_n, Wv_n, WT);

  const int gN = (N_NODES + 127) / 128;  // 391
  const int gE = E_EDGES / 128;          // 3125

  // all_feats = feats @ Wprep (identical for both mp; compute once)
  proj<128, 1, true><<<gN, 256, 0, stream>>>(
      nullptr, feats, WT + (size_t)24 * 16384, fprep, nullptr, nullptr, 128, 0, 0, N_NODES);

  for (int mp = 0; mp < NMPC; ++mp) {
    unsigned short *fchi = fprep, *fnhi = fa;
    for (int l = 0; l < DEPTHC; ++l) {
      const int ml = mp * 2 + l;
      const unsigned short* base = WT + (size_t)ml * 6 * 16384;
      if (l == 0) {
        proj<128, 2, false><<<gN, 256, 0, stream>>>(
            fchi, nullptr, base, KVn, KVn + 128, nullptr, 256, 256, 0, N_NODES);
        proj<128, 1, true><<<gN, 256, 0, stream>>>(
            nullptr, node_emb, base + (size_t)2 * 16384, Qn, nullptr, nullptr, 128, 0, 0, N_NODES);
        // fused: edge prep (emb @ Wedgeprep) + K/V production + Q-proj + attention
        edge_fused<1><<<gE, 256, 0, stream>>>(
            ehi, base + (size_t)3 * 16384, KVn, adj + (size_t)mp * E_EDGES * 2, KVe,
            edge_emb + (size_t)mp * E_EDGES * EDIMC, WT + (size_t)(25 + mp) * 16384);
      } else {
        proj<128, 3, false><<<gN, 256, 0, stream>>>(
            fchi, nullptr, base, KVn, KVn + 128, Qn, 256, 256, 128, N_NODES);
        edge_fused<0><<<gE, 256, 0, stream>>>(
            ehi, base + (size_t)3 * 16384, KVn, adj + (size_t)mp * E_EDGES * 2, KVe,
            nullptr, nullptr);
      }
      node_attn<<<N_NODES / 4, 256, 0, stream>>>(
          (const unsigned int*)Qn, (const unsigned int*)KVe,
          n2e + (size_t)mp * N_NODES * S_NEI, fnhi,
          out + (size_t)mp * N_NODES * 256 + (size_t)l * 128);

      fchi = fnhi; fnhi = fb;
    }
  }
}

// Round 10
// 1229.695 us; speedup vs baseline: 1.0422x; 1.0422x over previous
//
#include <hip/hip_runtime.h>

#define N_NODES 50000
#define S_NEI 16
#define E_EDGES 400000
#define DDIM 128
#define EDIMC 64
#define NMPC 2
#define DEPTHC 2

typedef __attribute__((ext_vector_type(8))) short short8v;
typedef __attribute__((ext_vector_type(4))) float float4v;

__device__ __forceinline__ unsigned short f2bf(float f) {
  unsigned int u = __float_as_uint(f);
  unsigned int r = (u + 0x7fffu + ((u >> 16) & 1u)) >> 16;
  return (unsigned short)r;
}
__device__ __forceinline__ float bf2f(unsigned short h) { return __uint_as_float((unsigned int)h << 16); }
__device__ __forceinline__ float bflo(unsigned int u) { return __uint_as_float(u << 16); }
__device__ __forceinline__ float bfhi(unsigned int u) { return __uint_as_float(u & 0xffff0000u); }

// ---------------------------------------------------------------------------
// Weight table: 27 slots x 16384 bf16.
//  slots ml*6 + {0:k_e, 1:v_e, 2:q_n, 3:q_e, 4:k_n, 5:v_n}  (ml = mp*2+l), each [c=128][d=128]
//  slot 24: Wprep^T [c=128][d=128]; slots 25,26: Wedgeprep[mp]^T [c=128][k=64] zero-padded
// ---------------------------------------------------------------------------
__global__ void build_wt(const float* __restrict__ Wprep, const float* __restrict__ Wedgeprep,
                         const float* __restrict__ Wq_e, const float* __restrict__ Wk_e,
                         const float* __restrict__ Wv_e, const float* __restrict__ Wq_n,
                         const float* __restrict__ Wk_n, const float* __restrict__ Wv_n,
                         unsigned short* __restrict__ WT) {
  int idx = blockIdx.x * 256 + threadIdx.x;
  if (idx >= 27 * 16384) return;
  int slot = idx >> 14, r = idx & 16383;
  float v = 0.f;
  if (slot < 24) {
    int ml = slot / 6, mat = slot % 6;
    int c = r >> 7, d = r & 127;
    int h = c >> 5, kk = c & 31;
    const float* W = (mat == 0) ? Wk_e : (mat == 1) ? Wv_e : (mat == 2) ? Wq_n
                   : (mat == 3) ? Wq_e : (mat == 4) ? Wk_n : Wv_n;
    v = W[(((size_t)ml * 4 + h) * 128 + d) * 32 + kk];
  } else if (slot == 24) {
    int c = r >> 7, d = r & 127;
    v = Wprep[d * 128 + c];
  } else {
    int mp = slot - 25;
    int c = r >> 6, k = r & 63;
    if (c < 128) v = Wedgeprep[((size_t)mp * 64 + k) * 128 + c];
  }
  WT[idx] = f2bf(v);
}

// ---------------------------------------------------------------------------
// proj: Y_w[m][c] = bf16( X[m][:] @ W_w ), per-output row stride rs_w (u16 units)
// ---------------------------------------------------------------------------
template<int KDIM, int NW, bool ASPLIT>
__global__ __launch_bounds__(256, 3)
void proj(const unsigned short* __restrict__ Xbf, const float* __restrict__ Xf,
          const unsigned short* __restrict__ WT,
          unsigned short* __restrict__ Y0, unsigned short* __restrict__ Y1,
          unsigned short* __restrict__ Y2, int rs0, int rs1, int rs2, int M) {
  constexpr int NKK  = KDIM / 32;
  constexpr int CHPR = KDIM / 8;
  constexpr int SWZ  = CHPR - 1;
  __shared__ unsigned short Wl[128 * KDIM];
  const int tid  = threadIdx.x;
  const int lane = tid & 63;
  const int wv   = tid >> 6;
  const int l15  = lane & 15, lg = lane >> 4;
  const long m0  = (long)blockIdx.x * 128 + wv * 32;

  short8v xb[2][NKK];
  #pragma unroll
  for (int rf = 0; rf < 2; ++rf) {
    long row = m0 + rf * 16 + l15; if (row >= M) row = M - 1;
    #pragma unroll
    for (int kk = 0; kk < NKK; ++kk) {
      const int k0 = kk * 32 + lg * 8;
      if (ASPLIT) {
        const float* p = Xf + row * KDIM + k0;
        float4v a0 = *(const float4v*)p;
        float4v a1 = *(const float4v*)(p + 4);
        #pragma unroll
        for (int j = 0; j < 8; ++j) {
          float x = (j < 4) ? a0[j] : a1[j - 4];
          xb[rf][kk][j] = (short)f2bf(x);
        }
      } else {
        xb[rf][kk] = *(const short8v*)(Xbf + row * KDIM + k0);
      }
    }
  }

  unsigned short* Ys[3] = {Y0, Y1, Y2};
  const int rsv[3] = {rs0, rs1, rs2};
  #pragma unroll
  for (int w = 0; w < NW; ++w) {
    if (w) __syncthreads();
    {
      const uint4* src = (const uint4*)(WT + (size_t)w * 16384);
      #pragma unroll
      for (int i = 0; i < CHPR / 2; ++i) {
        int ci = i * 256 + tid;
        int row = ci / CHPR, ch = ci & SWZ;
        uint4 v = src[ci];
        *(uint4*)((char*)Wl + row * (KDIM * 2) + ((ch ^ (row & SWZ)) << 4)) = v;
      }
    }
    __syncthreads();

    float4v acc[8][2];
    #pragma unroll
    for (int cf = 0; cf < 8; ++cf)
      #pragma unroll
      for (int rf = 0; rf < 2; ++rf) acc[cf][rf] = (float4v)0.f;

    #pragma unroll
    for (int kk = 0; kk < NKK; ++kk) {
      #pragma unroll
      for (int cf = 0; cf < 8; ++cf) {
        const int row = cf * 16 + l15;
        const int ch  = (kk * 4 + lg) ^ (row & SWZ);
        short8v b = *(const short8v*)((char*)Wl + row * (KDIM * 2) + (ch << 4));
        acc[cf][0] = __builtin_amdgcn_mfma_f32_16x16x32_bf16(b, xb[0][kk], acc[cf][0], 0, 0, 0);
        acc[cf][1] = __builtin_amdgcn_mfma_f32_16x16x32_bf16(b, xb[1][kk], acc[cf][1], 0, 0, 0);
      }
    }

    #pragma unroll
    for (int rf = 0; rf < 2; ++rf) {
      const long m = m0 + rf * 16 + l15;
      if (m < M) {
        #pragma unroll
        for (int cf = 0; cf < 8; ++cf) {
          const int c0 = cf * 16 + lg * 4;
          float4v a = acc[cf][rf];
          ushort4 o;
          o.x = f2bf(a[0]); o.y = f2bf(a[1]); o.z = f2bf(a[2]); o.w = f2bf(a[3]);
          *(ushort4*)(Ys[w] + m * (long)rsv[w] + c0) = o;
        }
      }
    }
  }
}

// ---------------------------------------------------------------------------
// edge_fused<PREP>: 512 threads / 8 waves, 16 edge rows per wave (halved
// per-wave register state vs the 256-thread version -> higher occupancy to
// hide gather/store latency). Per 128-edge tile:
//  PREP (layer 0): state = bf16(emb @ Wedgeprep) via MFMA + LDS transpose.
//  ph0/ph1: K_n/V_n projection -> KVe (interleaved 512B/edge, fragment stores)
//  ph2:     Q_e projection -> accQ (f32 regs)
//  tail:    2-endpoint attention in fragment layout over KVn + elu -> ehi.
// E divisible by 128; no guards.
// ---------------------------------------------------------------------------
template<int PREP>
__global__ __launch_bounds__(512, 4)
void edge_fused(unsigned short* __restrict__ ehi, const unsigned short* __restrict__ WTqe,
                const unsigned short* __restrict__ KVn, const int* __restrict__ adj,
                unsigned short* __restrict__ KVe,
                const float* __restrict__ emb, const unsigned short* __restrict__ WTprep) {
  __shared__ unsigned short Wl[128 * 128];
  const int tid  = threadIdx.x;
  const int lane = tid & 63;
  const int wv   = tid >> 6;          // 0..7
  const int l15  = lane & 15, lg = lane >> 4;
  const long m0  = (long)blockIdx.x * 128 + wv * 16;

  short8v xb[4];
  if (PREP) {
    // ---- stage Wedgeprep^T [c=128][k=64] bf16 = 16KB (8 chunks/row, SWZ=7) ----
    {
      const uint4* src = (const uint4*)WTprep;
      #pragma unroll
      for (int i = 0; i < 2; ++i) {
        int ci = i * 512 + tid;
        int row = ci >> 3, ch = ci & 7;
        uint4 v = src[ci];
        *(uint4*)((char*)Wl + row * 128 + ((ch ^ (row & 7)) << 4)) = v;
      }
    }
    // ---- emb fragments (f32 -> bf16), KDIM=64 ----
    short8v eb[2];
    {
      const long row = m0 + l15;
      #pragma unroll
      for (int kk = 0; kk < 2; ++kk) {
        const float* p = emb + row * 64 + kk * 32 + lg * 8;
        float4v a0 = *(const float4v*)p;
        float4v a1 = *(const float4v*)(p + 4);
        #pragma unroll
        for (int j = 0; j < 8; ++j) {
          float x = (j < 4) ? a0[j] : a1[j - 4];
          eb[kk][j] = (short)f2bf(x);
        }
      }
    }
    __syncthreads();
    float4v accP[8];
    #pragma unroll
    for (int cf = 0; cf < 8; ++cf) accP[cf] = (float4v)0.f;
    #pragma unroll
    for (int kk = 0; kk < 2; ++kk) {
      #pragma unroll
      for (int cf = 0; cf < 8; ++cf) {
        const int row = cf * 16 + l15;
        const int ch  = (kk * 4 + lg) ^ (row & 7);
        short8v b = *(const short8v*)((char*)Wl + row * 128 + (ch << 4));
        accP[cf] = __builtin_amdgcn_mfma_f32_16x16x32_bf16(b, eb[kk], accP[cf], 0, 0, 0);
      }
    }
    __syncthreads();  // all W reads done before overwrite
    // ---- dump state bf16 -> LDS [er=128][c=128], 16B-chunk XOR swizzle ----
    {
      const int er = wv * 16 + l15;
      #pragma unroll
      for (int cf = 0; cf < 8; ++cf) {
        float4v a = accP[cf];
        ushort4 o;
        o.x = f2bf(a[0]); o.y = f2bf(a[1]); o.z = f2bf(a[2]); o.w = f2bf(a[3]);
        const int ch16 = cf * 2 + (lg >> 1);
        const int off  = er * 256 + ((ch16 ^ (er & 15)) << 4) + (lg & 1) * 8;
        *(ushort4*)((char*)Wl + off) = o;
      }
    }
    __syncthreads();
    // ---- read back as B-fragments ----
    {
      const int row = wv * 16 + l15;
      #pragma unroll
      for (int kk = 0; kk < 4; ++kk) {
        const int ch = (kk * 4 + lg) ^ (row & 15);
        xb[kk] = *(const short8v*)((char*)Wl + row * 256 + (ch << 4));
      }
    }
  } else {
    const long row = m0 + l15;
    #pragma unroll
    for (int kk = 0; kk < 4; ++kk)
      xb[kk] = *(const short8v*)(ehi + row * 128 + kk * 32 + lg * 8);
  }

  float4v accQ[8];
  // phase 0: k_n (slot 1), phase 1: v_n (slot 2), phase 2: q_e (slot 0)
  const int slot_of[3] = {1, 2, 0};
  #pragma unroll
  for (int ph = 0; ph < 3; ++ph) {
    if (ph || PREP) __syncthreads();
    {
      const uint4* src = (const uint4*)(WTqe + (size_t)slot_of[ph] * 16384);
      #pragma unroll
      for (int i = 0; i < 4; ++i) {
        int ci = i * 512 + tid;
        int row = ci >> 4, ch = ci & 15;
        uint4 v = src[ci];
        *(uint4*)((char*)Wl + row * 256 + ((ch ^ (row & 15)) << 4)) = v;
      }
    }
    __syncthreads();

    float4v acc[8];
    #pragma unroll
    for (int cf = 0; cf < 8; ++cf) acc[cf] = (float4v)0.f;

    #pragma unroll
    for (int kk = 0; kk < 4; ++kk) {
      #pragma unroll
      for (int cf = 0; cf < 8; ++cf) {
        const int row = cf * 16 + l15;
        const int ch  = (kk * 4 + lg) ^ (row & 15);
        short8v b = *(const short8v*)((char*)Wl + row * 256 + (ch << 4));
        acc[cf] = __builtin_amdgcn_mfma_f32_16x16x32_bf16(b, xb[kk], acc[cf], 0, 0, 0);
      }
    }

    if (ph < 2) {
      const long m = m0 + l15;
      #pragma unroll
      for (int cf = 0; cf < 8; ++cf) {
        const int c0 = cf * 16 + lg * 4;
        float4v a = acc[cf];
        ushort4 o;
        o.x = f2bf(a[0]); o.y = f2bf(a[1]); o.z = f2bf(a[2]); o.w = f2bf(a[3]);
        *(ushort4*)(KVe + m * 256 + ph * 128 + c0) = o;
      }
    } else {
      #pragma unroll
      for (int cf = 0; cf < 8; ++cf) accQ[cf] = acc[cf];
    }
  }

  // ---- attention over 2 endpoints (fragment layout) ----
  const float scale = 0.17677669529663687f;  // 1/sqrt(32)
  {
    const long e = m0 + l15;
    const int2 nn = *(const int2*)(adj + e * 2);
    const size_t b0 = (size_t)nn.x * 256, b1 = (size_t)nn.y * 256;
    float p0[4] = {0.f, 0.f, 0.f, 0.f}, p1[4] = {0.f, 0.f, 0.f, 0.f};
    #pragma unroll
    for (int cf = 0; cf < 8; ++cf) {
      const int c0 = cf * 16 + lg * 4;
      const int h = cf >> 1;
      ushort4 k0 = *(const ushort4*)(KVn + b0 + c0);
      ushort4 k1 = *(const ushort4*)(KVn + b1 + c0);
      float4v q = accQ[cf];
      p0[h] += q[0] * bf2f(k0.x) + q[1] * bf2f(k0.y) + q[2] * bf2f(k0.z) + q[3] * bf2f(k0.w);
      p1[h] += q[0] * bf2f(k1.x) + q[1] * bf2f(k1.y) + q[2] * bf2f(k1.z) + q[3] * bf2f(k1.w);
    }
    float a0[4], a1[4];
    #pragma unroll
    for (int h = 0; h < 4; ++h) {
      p0[h] += __shfl_xor(p0[h], 16); p0[h] += __shfl_xor(p0[h], 32);
      p1[h] += __shfl_xor(p1[h], 16); p1[h] += __shfl_xor(p1[h], 32);
      const float s0 = p0[h] * scale, s1 = p1[h] * scale;
      const float mx = fmaxf(s0, s1);
      const float e0 = __expf(s0 - mx), e1 = __expf(s1 - mx);
      const float inv = 1.0f / (e0 + e1);
      a0[h] = e0 * inv; a1[h] = e1 * inv;
    }
    #pragma unroll
    for (int cf = 0; cf < 8; ++cf) {
      const int c0 = cf * 16 + lg * 4;
      const int h = cf >> 1;
      ushort4 v0 = *(const ushort4*)(KVn + b0 + 128 + c0);
      ushort4 v1 = *(const ushort4*)(KVn + b1 + 128 + c0);
      float o[4];
      o[0] = a0[h] * bf2f(v0.x) + a1[h] * bf2f(v1.x);
      o[1] = a0[h] * bf2f(v0.y) + a1[h] * bf2f(v1.y);
      o[2] = a0[h] * bf2f(v0.z) + a1[h] * bf2f(v1.z);
      o[3] = a0[h] * bf2f(v0.w) + a1[h] * bf2f(v1.w);
      o[0] = o[0] > 0.f ? o[0] : expm1f(o[0]);
      o[1] = o[1] > 0.f ? o[1] : expm1f(o[1]);
      o[2] = o[2] > 0.f ? o[2] : expm1f(o[2]);
      o[3] = o[3] > 0.f ? o[3] : expm1f(o[3]);
      ushort4 ob;
      ob.x = f2bf(o[0]); ob.y = f2bf(o[1]); ob.z = f2bf(o[2]); ob.w = f2bf(o[3]);
      *(ushort4*)(ehi + e * 128 + c0) = ob;
    }
  }
}

// ---------------------------------------------------------------------------
// node_attn: one wave per node, 16 incident edges, K/V gathered from
// interleaved KVe (512B per edge). Writes bf16 next-state + f32 output slice.
// ---------------------------------------------------------------------------
__global__ __launch_bounds__(256)
void node_attn(const unsigned int* __restrict__ Qn, const unsigned int* __restrict__ KVe,
               const int* __restrict__ n2e,
               unsigned short* __restrict__ fhi, float* __restrict__ outp) {
  const int lane = threadIdx.x & 63;
  const long n = (long)blockIdx.x * 4 + (threadIdx.x >> 6);
  const unsigned int q = Qn[n * 64 + lane];
  const float qa = bflo(q), qb = bfhi(q);
  float sc[16];
  unsigned int vv[16];
  #pragma unroll
  for (int s = 0; s < 16; ++s) {
    const long e = n2e[n * 16 + s];
    const unsigned int kk = KVe[e * 128 + lane];
    vv[s] = KVe[e * 128 + 64 + lane];
    float p = qa * bflo(kk) + qb * bfhi(kk);
    #pragma unroll
    for (int off = 1; off < 16; off <<= 1) p += __shfl_xor(p, off);
    sc[s] = p * 0.17677669529663687f;
  }
  float m = sc[0];
  #pragma unroll
  for (int s = 1; s < 16; ++s) m = fmaxf(m, sc[s]);
  float sum = 0.f;
  #pragma unroll
  for (int s = 0; s < 16; ++s) { sc[s] = __expf(sc[s] - m); sum += sc[s]; }
  const float inv = 1.0f / sum;
  float oa = 0.f, ob = 0.f;
  #pragma unroll
  for (int s = 0; s < 16; ++s) { oa += sc[s] * bflo(vv[s]); ob += sc[s] * bfhi(vv[s]); }
  oa *= inv; ob *= inv;
  oa = oa > 0.f ? oa : expm1f(oa);
  ob = ob > 0.f ? ob : expm1f(ob);
  ((unsigned int*)fhi)[n * 64 + lane] = (unsigned int)f2bf(oa) | ((unsigned int)f2bf(ob) << 16);
  *(float2*)(outp + n * 256 + lane * 2) = make_float2(oa, ob);
}

extern "C" void kernel_launch(void* const* d_in, const int* in_sizes, int n_in,
                              void* d_out, int out_size, void* d_ws, size_t ws_size,
                              hipStream_t stream) {
  const float* feats     = (const float*)d_in[0];
  const float* node_emb  = (const float*)d_in[1];
  const float* Wprep     = (const float*)d_in[2];
  const float* edge_emb  = (const float*)d_in[3];
  const float* Wedgeprep = (const float*)d_in[4];
  const float* Wq_e      = (const float*)d_in[5];
  const float* Wk_e      = (const float*)d_in[6];
  const float* Wv_e      = (const float*)d_in[7];
  const float* Wq_n      = (const float*)d_in[8];
  const float* Wk_n      = (const float*)d_in[9];
  const float* Wv_n      = (const float*)d_in[10];
  const int*   n2e       = (const int*)d_in[11];
  const int*   adj       = (const int*)d_in[12];
  float* out = (float*)d_out;

  char* w = (char*)d_ws;
  auto carve = [&](size_t bytes) -> char* {
    char* p = w; w += (bytes + 255) & ~(size_t)255; return p;
  };
  unsigned short* ehi   = (unsigned short*)carve((size_t)E_EDGES * 128 * 2);
  unsigned short* fprep = (unsigned short*)carve((size_t)N_NODES * 128 * 2);  // all_feats (both mp)
  unsigned short* fa    = (unsigned short*)carve((size_t)N_NODES * 128 * 2);
  unsigned short* fb    = (unsigned short*)carve((size_t)N_NODES * 128 * 2);
  unsigned short* KVe   = (unsigned short*)carve((size_t)E_EDGES * 256 * 2);  // interleaved K|V
  unsigned short* KVn   = (unsigned short*)carve((size_t)N_NODES * 256 * 2);  // interleaved K|V
  unsigned short* Qn    = (unsigned short*)carve((size_t)N_NODES * 128 * 2);
  unsigned short* WT    = (unsigned short*)carve((size_t)27 * 16384 * 2);

  build_wt<<<(27 * 16384 + 255) / 256, 256, 0, stream>>>(
      Wprep, Wedgeprep, Wq_e, Wk_e, Wv_e, Wq_n, Wk_n, Wv_n, WT);

  const int gN = (N_NODES + 127) / 128;  // 391
  const int gE = E_EDGES / 128;          // 3125

  // all_feats = feats @ Wprep (identical for both mp; compute once)
  proj<128, 1, true><<<gN, 256, 0, stream>>>(
      nullptr, feats, WT + (size_t)24 * 16384, fprep, nullptr, nullptr, 128, 0, 0, N_NODES);

  for (int mp = 0; mp < NMPC; ++mp) {
    unsigned short *fchi = fprep, *fnhi = fa;
    for (int l = 0; l < DEPTHC; ++l) {
      const int ml = mp * 2 + l;
      const unsigned short* base = WT + (size_t)ml * 6 * 16384;
      if (l == 0) {
        proj<128, 2, false><<<gN, 256, 0, stream>>>(
            fchi, nullptr, base, KVn, KVn + 128, nullptr, 256, 256, 0, N_NODES);
        proj<128, 1, true><<<gN, 256, 0, stream>>>(
            nullptr, node_emb, base + (size_t)2 * 16384, Qn, nullptr, nullptr, 128, 0, 0, N_NODES);
        // fused: edge prep (emb @ Wedgeprep) + K/V production + Q-proj + attention
        edge_fused<1><<<gE, 512, 0, stream>>>(
            ehi, base + (size_t)3 * 16384, KVn, adj + (size_t)mp * E_EDGES * 2, KVe,
            edge_emb + (size_t)mp * E_EDGES * EDIMC, WT + (size_t)(25 + mp) * 16384);
      } else {
        proj<128, 3, false><<<gN, 256, 0, stream>>>(
            fchi, nullptr, base, KVn, KVn + 128, Qn, 256, 256, 128, N_NODES);
        edge_fused<0><<<gE, 512, 0, stream>>>(
            ehi, base + (size_t)3 * 16384, KVn, adj + (size_t)mp * E_EDGES * 2, KVe,
            nullptr, nullptr);
      }
      node_attn<<<N_NODES / 4, 256, 0, stream>>>(
          (const unsigned int*)Qn, (const unsigned int*)KVe,
          n2e + (size_t)mp * N_NODES * S_NEI, fnhi,
          out + (size_t)mp * N_NODES * 256 + (size_t)l * 128);

      fchi = fnhi; fnhi = fb;
    }
  }
}

// Round 11
// 1211.921 us; speedup vs baseline: 1.0574x; 1.0147x over previous
//
#include <hip/hip_runtime.h>

#define N_NODES 50000
#define S_NEI 16
#define E_EDGES 400000
#define DDIM 128
#define EDIMC 64
#define NMPC 2
#define DEPTHC 2

typedef __attribute__((ext_vector_type(8))) short short8v;
typedef __attribute__((ext_vector_type(4))) float float4v;

__device__ __forceinline__ unsigned short f2bf(float f) {
  unsigned int u = __float_as_uint(f);
  unsigned int r = (u + 0x7fffu + ((u >> 16) & 1u)) >> 16;
  return (unsigned short)r;
}
__device__ __forceinline__ float bf2f(unsigned short h) { return __uint_as_float((unsigned int)h << 16); }
__device__ __forceinline__ float bflo(unsigned int u) { return __uint_as_float(u << 16); }
__device__ __forceinline__ float bfhi(unsigned int u) { return __uint_as_float(u & 0xffff0000u); }

// ---------------------------------------------------------------------------
// Weight table: 27 slots x 16384 bf16.
//  slots ml*6 + {0:k_e, 1:v_e, 2:q_n, 3:q_e, 4:k_n, 5:v_n}  (ml = mp*2+l), each [c=128][d=128]
//  slot 24: Wprep^T [c=128][d=128]; slots 25,26: Wedgeprep[mp]^T [c=128][k=64] zero-padded
// ---------------------------------------------------------------------------
__global__ void build_wt(const float* __restrict__ Wprep, const float* __restrict__ Wedgeprep,
                         const float* __restrict__ Wq_e, const float* __restrict__ Wk_e,
                         const float* __restrict__ Wv_e, const float* __restrict__ Wq_n,
                         const float* __restrict__ Wk_n, const float* __restrict__ Wv_n,
                         unsigned short* __restrict__ WT) {
  int idx = blockIdx.x * 256 + threadIdx.x;
  if (idx >= 27 * 16384) return;
  int slot = idx >> 14, r = idx & 16383;
  float v = 0.f;
  if (slot < 24) {
    int ml = slot / 6, mat = slot % 6;
    int c = r >> 7, d = r & 127;
    int h = c >> 5, kk = c & 31;
    const float* W = (mat == 0) ? Wk_e : (mat == 1) ? Wv_e : (mat == 2) ? Wq_n
                   : (mat == 3) ? Wq_e : (mat == 4) ? Wk_n : Wv_n;
    v = W[(((size_t)ml * 4 + h) * 128 + d) * 32 + kk];
  } else if (slot == 24) {
    int c = r >> 7, d = r & 127;
    v = Wprep[d * 128 + c];
  } else {
    int mp = slot - 25;
    int c = r >> 6, k = r & 63;
    if (c < 128) v = Wedgeprep[((size_t)mp * 64 + k) * 128 + c];
  }
  WT[idx] = f2bf(v);
}

// ---------------------------------------------------------------------------
// proj: Y_w[m][c] = bf16( X[m][:] @ W_w ), per-output row stride rs_w (u16 units)
// ---------------------------------------------------------------------------
template<int KDIM, int NW, bool ASPLIT>
__global__ __launch_bounds__(256, 3)
void proj(const unsigned short* __restrict__ Xbf, const float* __restrict__ Xf,
          const unsigned short* __restrict__ WT,
          unsigned short* __restrict__ Y0, unsigned short* __restrict__ Y1,
          unsigned short* __restrict__ Y2, int rs0, int rs1, int rs2, int M) {
  constexpr int NKK  = KDIM / 32;
  constexpr int CHPR = KDIM / 8;
  constexpr int SWZ  = CHPR - 1;
  __shared__ unsigned short Wl[128 * KDIM];
  const int tid  = threadIdx.x;
  const int lane = tid & 63;
  const int wv   = tid >> 6;
  const int l15  = lane & 15, lg = lane >> 4;
  const long m0  = (long)blockIdx.x * 128 + wv * 32;

  short8v xb[2][NKK];
  #pragma unroll
  for (int rf = 0; rf < 2; ++rf) {
    long row = m0 + rf * 16 + l15; if (row >= M) row = M - 1;
    #pragma unroll
    for (int kk = 0; kk < NKK; ++kk) {
      const int k0 = kk * 32 + lg * 8;
      if (ASPLIT) {
        const float* p = Xf + row * KDIM + k0;
        float4v a0 = *(const float4v*)p;
        float4v a1 = *(const float4v*)(p + 4);
        #pragma unroll
        for (int j = 0; j < 8; ++j) {
          float x = (j < 4) ? a0[j] : a1[j - 4];
          xb[rf][kk][j] = (short)f2bf(x);
        }
      } else {
        xb[rf][kk] = *(const short8v*)(Xbf + row * KDIM + k0);
      }
    }
  }

  unsigned short* Ys[3] = {Y0, Y1, Y2};
  const int rsv[3] = {rs0, rs1, rs2};
  #pragma unroll
  for (int w = 0; w < NW; ++w) {
    if (w) __syncthreads();
    {
      const uint4* src = (const uint4*)(WT + (size_t)w * 16384);
      #pragma unroll
      for (int i = 0; i < CHPR / 2; ++i) {
        int ci = i * 256 + tid;
        int row = ci / CHPR, ch = ci & SWZ;
        uint4 v = src[ci];
        *(uint4*)((char*)Wl + row * (KDIM * 2) + ((ch ^ (row & SWZ)) << 4)) = v;
      }
    }
    __syncthreads();

    float4v acc[8][2];
    #pragma unroll
    for (int cf = 0; cf < 8; ++cf)
      #pragma unroll
      for (int rf = 0; rf < 2; ++rf) acc[cf][rf] = (float4v)0.f;

    #pragma unroll
    for (int kk = 0; kk < NKK; ++kk) {
      #pragma unroll
      for (int cf = 0; cf < 8; ++cf) {
        const int row = cf * 16 + l15;
        const int ch  = (kk * 4 + lg) ^ (row & SWZ);
        short8v b = *(const short8v*)((char*)Wl + row * (KDIM * 2) + (ch << 4));
        acc[cf][0] = __builtin_amdgcn_mfma_f32_16x16x32_bf16(b, xb[0][kk], acc[cf][0], 0, 0, 0);
        acc[cf][1] = __builtin_amdgcn_mfma_f32_16x16x32_bf16(b, xb[1][kk], acc[cf][1], 0, 0, 0);
      }
    }

    #pragma unroll
    for (int rf = 0; rf < 2; ++rf) {
      const long m = m0 + rf * 16 + l15;
      if (m < M) {
        #pragma unroll
        for (int cf = 0; cf < 8; ++cf) {
          const int c0 = cf * 16 + lg * 4;
          float4v a = acc[cf][rf];
          ushort4 o;
          o.x = f2bf(a[0]); o.y = f2bf(a[1]); o.z = f2bf(a[2]); o.w = f2bf(a[3]);
          *(ushort4*)(Ys[w] + m * (long)rsv[w] + c0) = o;
        }
      }
    }
  }
}

// ---------------------------------------------------------------------------
// edge_fused<PREP>: 512 threads / 8 waves, 16 edge rows per wave.
//  PREP (layer 0): state = bf16(emb @ Wedgeprep) via MFMA + LDS transpose.
//  ph0/ph1: K_n/V_n projection -> KVe (interleaved 512B/edge, fragment stores)
//  ph2:     Q_e projection -> accQ; K-gathers issued just before Q-MFMA so
//           their HBM latency hides under the MFMA phase (T14 pattern).
//  tail:    2-endpoint attention (K prefetched, V loaded in tail) + elu -> ehi.
// E divisible by 128; no guards.
// ---------------------------------------------------------------------------
template<int PREP>
__global__ __launch_bounds__(512, 4)
void edge_fused(unsigned short* __restrict__ ehi, const unsigned short* __restrict__ WTqe,
                const unsigned short* __restrict__ KVn, const int* __restrict__ adj,
                unsigned short* __restrict__ KVe,
                const float* __restrict__ emb, const unsigned short* __restrict__ WTprep) {
  __shared__ unsigned short Wl[128 * 128];
  const int tid  = threadIdx.x;
  const int lane = tid & 63;
  const int wv   = tid >> 6;          // 0..7
  const int l15  = lane & 15, lg = lane >> 4;
  const long m0  = (long)blockIdx.x * 128 + wv * 16;

  // tail gather addresses (independent of all compute)
  const long e = m0 + l15;
  const int2 nn = *(const int2*)(adj + e * 2);
  const size_t b0 = (size_t)nn.x * 256, b1 = (size_t)nn.y * 256;

  short8v xb[4];
  if (PREP) {
    // ---- stage Wedgeprep^T [c=128][k=64] bf16 = 16KB (8 chunks/row, SWZ=7) ----
    {
      const uint4* src = (const uint4*)WTprep;
      #pragma unroll
      for (int i = 0; i < 2; ++i) {
        int ci = i * 512 + tid;
        int row = ci >> 3, ch = ci & 7;
        uint4 v = src[ci];
        *(uint4*)((char*)Wl + row * 128 + ((ch ^ (row & 7)) << 4)) = v;
      }
    }
    // ---- emb fragments (f32 -> bf16), KDIM=64 ----
    short8v eb[2];
    {
      const long row = m0 + l15;
      #pragma unroll
      for (int kk = 0; kk < 2; ++kk) {
        const float* p = emb + row * 64 + kk * 32 + lg * 8;
        float4v a0 = *(const float4v*)p;
        float4v a1 = *(const float4v*)(p + 4);
        #pragma unroll
        for (int j = 0; j < 8; ++j) {
          float x = (j < 4) ? a0[j] : a1[j - 4];
          eb[kk][j] = (short)f2bf(x);
        }
      }
    }
    __syncthreads();
    float4v accP[8];
    #pragma unroll
    for (int cf = 0; cf < 8; ++cf) accP[cf] = (float4v)0.f;
    #pragma unroll
    for (int kk = 0; kk < 2; ++kk) {
      #pragma unroll
      for (int cf = 0; cf < 8; ++cf) {
        const int row = cf * 16 + l15;
        const int ch  = (kk * 4 + lg) ^ (row & 7);
        short8v b = *(const short8v*)((char*)Wl + row * 128 + (ch << 4));
        accP[cf] = __builtin_amdgcn_mfma_f32_16x16x32_bf16(b, eb[kk], accP[cf], 0, 0, 0);
      }
    }
    __syncthreads();  // all W reads done before overwrite
    // ---- dump state bf16 -> LDS [er=128][c=128], 16B-chunk XOR swizzle ----
    {
      const int er = wv * 16 + l15;
      #pragma unroll
      for (int cf = 0; cf < 8; ++cf) {
        float4v a = accP[cf];
        ushort4 o;
        o.x = f2bf(a[0]); o.y = f2bf(a[1]); o.z = f2bf(a[2]); o.w = f2bf(a[3]);
        const int ch16 = cf * 2 + (lg >> 1);
        const int off  = er * 256 + ((ch16 ^ (er & 15)) << 4) + (lg & 1) * 8;
        *(ushort4*)((char*)Wl + off) = o;
      }
    }
    __syncthreads();
    // ---- read back as B-fragments ----
    {
      const int row = wv * 16 + l15;
      #pragma unroll
      for (int kk = 0; kk < 4; ++kk) {
        const int ch = (kk * 4 + lg) ^ (row & 15);
        xb[kk] = *(const short8v*)((char*)Wl + row * 256 + (ch << 4));
      }
    }
  } else {
    const long row = m0 + l15;
    #pragma unroll
    for (int kk = 0; kk < 4; ++kk)
      xb[kk] = *(const short8v*)(ehi + row * 128 + kk * 32 + lg * 8);
  }

  float4v accQ[8];
  ushort4 gk0[8], gk1[8];   // prefetched K rows for the attention tail
  // phase 0: k_n (slot 1), phase 1: v_n (slot 2), phase 2: q_e (slot 0)
  const int slot_of[3] = {1, 2, 0};
  #pragma unroll
  for (int ph = 0; ph < 3; ++ph) {
    if (ph || PREP) __syncthreads();
    {
      const uint4* src = (const uint4*)(WTqe + (size_t)slot_of[ph] * 16384);
      #pragma unroll
      for (int i = 0; i < 4; ++i) {
        int ci = i * 512 + tid;
        int row = ci >> 4, ch = ci & 15;
        uint4 v = src[ci];
        *(uint4*)((char*)Wl + row * 256 + ((ch ^ (row & 15)) << 4)) = v;
      }
    }
    __syncthreads();

    if (ph == 2) {
      // issue K gathers now: latency hides under the Q-MFMA phase below
      #pragma unroll
      for (int cf = 0; cf < 8; ++cf) {
        const int c0 = cf * 16 + lg * 4;
        gk0[cf] = *(const ushort4*)(KVn + b0 + c0);
        gk1[cf] = *(const ushort4*)(KVn + b1 + c0);
      }
    }

    float4v acc[8];
    #pragma unroll
    for (int cf = 0; cf < 8; ++cf) acc[cf] = (float4v)0.f;

    #pragma unroll
    for (int kk = 0; kk < 4; ++kk) {
      #pragma unroll
      for (int cf = 0; cf < 8; ++cf) {
        const int row = cf * 16 + l15;
        const int ch  = (kk * 4 + lg) ^ (row & 15);
        short8v b = *(const short8v*)((char*)Wl + row * 256 + (ch << 4));
        acc[cf] = __builtin_amdgcn_mfma_f32_16x16x32_bf16(b, xb[kk], acc[cf], 0, 0, 0);
      }
    }

    if (ph < 2) {
      const long m = m0 + l15;
      #pragma unroll
      for (int cf = 0; cf < 8; ++cf) {
        const int c0 = cf * 16 + lg * 4;
        float4v a = acc[cf];
        ushort4 o;
        o.x = f2bf(a[0]); o.y = f2bf(a[1]); o.z = f2bf(a[2]); o.w = f2bf(a[3]);
        *(ushort4*)(KVe + m * 256 + ph * 128 + c0) = o;
      }
    } else {
      #pragma unroll
      for (int cf = 0; cf < 8; ++cf) accQ[cf] = acc[cf];
    }
  }

  // ---- attention over 2 endpoints (fragment layout; K prefetched) ----
  const float scale = 0.17677669529663687f;  // 1/sqrt(32)
  {
    float p0[4] = {0.f, 0.f, 0.f, 0.f}, p1[4] = {0.f, 0.f, 0.f, 0.f};
    #pragma unroll
    for (int cf = 0; cf < 8; ++cf) {
      const int h = cf >> 1;
      ushort4 k0 = gk0[cf];
      ushort4 k1 = gk1[cf];
      float4v q = accQ[cf];
      p0[h] += q[0] * bf2f(k0.x) + q[1] * bf2f(k0.y) + q[2] * bf2f(k0.z) + q[3] * bf2f(k0.w);
      p1[h] += q[0] * bf2f(k1.x) + q[1] * bf2f(k1.y) + q[2] * bf2f(k1.z) + q[3] * bf2f(k1.w);
    }
    float a0[4], a1[4];
    #pragma unroll
    for (int h = 0; h < 4; ++h) {
      p0[h] += __shfl_xor(p0[h], 16); p0[h] += __shfl_xor(p0[h], 32);
      p1[h] += __shfl_xor(p1[h], 16); p1[h] += __shfl_xor(p1[h], 32);
      const float s0 = p0[h] * scale, s1 = p1[h] * scale;
      const float mx = fmaxf(s0, s1);
      const float e0 = __expf(s0 - mx), e1 = __expf(s1 - mx);
      const float inv = 1.0f / (e0 + e1);
      a0[h] = e0 * inv; a1[h] = e1 * inv;
    }
    #pragma unroll
    for (int cf = 0; cf < 8; ++cf) {
      const int c0 = cf * 16 + lg * 4;
      const int h = cf >> 1;
      ushort4 v0 = *(const ushort4*)(KVn + b0 + 128 + c0);
      ushort4 v1 = *(const ushort4*)(KVn + b1 + 128 + c0);
      float o[4];
      o[0] = a0[h] * bf2f(v0.x) + a1[h] * bf2f(v1.x);
      o[1] = a0[h] * bf2f(v0.y) + a1[h] * bf2f(v1.y);
      o[2] = a0[h] * bf2f(v0.z) + a1[h] * bf2f(v1.z);
      o[3] = a0[h] * bf2f(v0.w) + a1[h] * bf2f(v1.w);
      o[0] = o[0] > 0.f ? o[0] : expm1f(o[0]);
      o[1] = o[1] > 0.f ? o[1] : expm1f(o[1]);
      o[2] = o[2] > 0.f ? o[2] : expm1f(o[2]);
      o[3] = o[3] > 0.f ? o[3] : expm1f(o[3]);
      ushort4 ob;
      ob.x = f2bf(o[0]); ob.y = f2bf(o[1]); ob.z = f2bf(o[2]); ob.w = f2bf(o[3]);
      *(ushort4*)(ehi + e * 128 + c0) = ob;
    }
  }
}

// ---------------------------------------------------------------------------
// node_attn: one wave per node, 16 incident edges. All 32 K/V gather loads are
// issued up-front (static-indexed register arrays) so the 16 shfl-reduce trees
// overlap the gather latency instead of serializing on it.
// ---------------------------------------------------------------------------
__global__ __launch_bounds__(256)
void node_attn(const unsigned int* __restrict__ Qn, const unsigned int* __restrict__ KVe,
               const int* __restrict__ n2e,
               unsigned short* __restrict__ fhi, float* __restrict__ outp) {
  const int lane = threadIdx.x & 63;
  const long n = (long)blockIdx.x * 4 + (threadIdx.x >> 6);
  const unsigned int q = Qn[n * 64 + lane];
  unsigned int kk[16], vv[16];
  #pragma unroll
  for (int s = 0; s < 16; ++s) {
    const long e = n2e[n * 16 + s];
    kk[s] = KVe[e * 128 + lane];
    vv[s] = KVe[e * 128 + 64 + lane];
  }
  const float qa = bflo(q), qb = bfhi(q);
  float sc[16];
  #pragma unroll
  for (int s = 0; s < 16; ++s) {
    float p = qa * bflo(kk[s]) + qb * bfhi(kk[s]);
    #pragma unroll
    for (int off = 1; off < 16; off <<= 1) p += __shfl_xor(p, off);
    sc[s] = p * 0.17677669529663687f;
  }
  float m = sc[0];
  #pragma unroll
  for (int s = 1; s < 16; ++s) m = fmaxf(m, sc[s]);
  float sum = 0.f;
  #pragma unroll
  for (int s = 0; s < 16; ++s) { sc[s] = __expf(sc[s] - m); sum += sc[s]; }
  const float inv = 1.0f / sum;
  float oa = 0.f, ob = 0.f;
  #pragma unroll
  for (int s = 0; s < 16; ++s) { oa += sc[s] * bflo(vv[s]); ob += sc[s] * bfhi(vv[s]); }
  oa *= inv; ob *= inv;
  oa = oa > 0.f ? oa : expm1f(oa);
  ob = ob > 0.f ? ob : expm1f(ob);
  ((unsigned int*)fhi)[n * 64 + lane] = (unsigned int)f2bf(oa) | ((unsigned int)f2bf(ob) << 16);
  *(float2*)(outp + n * 256 + lane * 2) = make_float2(oa, ob);
}

extern "C" void kernel_launch(void* const* d_in, const int* in_sizes, int n_in,
                              void* d_out, int out_size, void* d_ws, size_t ws_size,
                              hipStream_t stream) {
  const float* feats     = (const float*)d_in[0];
  const float* node_emb  = (const float*)d_in[1];
  const float* Wprep     = (const float*)d_in[2];
  const float* edge_emb  = (const float*)d_in[3];
  const float* Wedgeprep = (const float*)d_in[4];
  const float* Wq_e      = (const float*)d_in[5];
  const float* Wk_e      = (const float*)d_in[6];
  const float* Wv_e      = (const float*)d_in[7];
  const float* Wq_n      = (const float*)d_in[8];
  const float* Wk_n      = (const float*)d_in[9];
  const float* Wv_n      = (const float*)d_in[10];
  const int*   n2e       = (const int*)d_in[11];
  const int*   adj       = (const int*)d_in[12];
  float* out = (float*)d_out;

  char* w = (char*)d_ws;
  auto carve = [&](size_t bytes) -> char* {
    char* p = w; w += (bytes + 255) & ~(size_t)255; return p;
  };
  unsigned short* ehi   = (unsigned short*)carve((size_t)E_EDGES * 128 * 2);
  unsigned short* fprep = (unsigned short*)carve((size_t)N_NODES * 128 * 2);  // all_feats (both mp)
  unsigned short* fa    = (unsigned short*)carve((size_t)N_NODES * 128 * 2);
  unsigned short* fb    = (unsigned short*)carve((size_t)N_NODES * 128 * 2);
  unsigned short* KVe   = (unsigned short*)carve((size_t)E_EDGES * 256 * 2);  // interleaved K|V
  unsigned short* KVn   = (unsigned short*)carve((size_t)N_NODES * 256 * 2);  // interleaved K|V
  unsigned short* Qn    = (unsigned short*)carve((size_t)N_NODES * 128 * 2);
  unsigned short* WT    = (unsigned short*)carve((size_t)27 * 16384 * 2);

  build_wt<<<(27 * 16384 + 255) / 256, 256, 0, stream>>>(
      Wprep, Wedgeprep, Wq_e, Wk_e, Wv_e, Wq_n, Wk_n, Wv_n, WT);

  const int gN = (N_NODES + 127) / 128;  // 391
  const int gE = E_EDGES / 128;          // 3125

  // all_feats = feats @ Wprep (identical for both mp; compute once)
  proj<128, 1, true><<<gN, 256, 0, stream>>>(
      nullptr, feats, WT + (size_t)24 * 16384, fprep, nullptr, nullptr, 128, 0, 0, N_NODES);

  for (int mp = 0; mp < NMPC; ++mp) {
    unsigned short *fchi = fprep, *fnhi = fa;
    for (int l = 0; l < DEPTHC; ++l) {
      const int ml = mp * 2 + l;
      const unsigned short* base = WT + (size_t)ml * 6 * 16384;
      if (l == 0) {
        proj<128, 2, false><<<gN, 256, 0, stream>>>(
            fchi, nullptr, base, KVn, KVn + 128, nullptr, 256, 256, 0, N_NODES);
        proj<128, 1, true><<<gN, 256, 0, stream>>>(
            nullptr, node_emb, base + (size_t)2 * 16384, Qn, nullptr, nullptr, 128, 0, 0, N_NODES);
        // fused: edge prep (emb @ Wedgeprep) + K/V production + Q-proj + attention
        edge_fused<1><<<gE, 512, 0, stream>>>(
            ehi, base + (size_t)3 * 16384, KVn, adj + (size_t)mp * E_EDGES * 2, KVe,
            edge_emb + (size_t)mp * E_EDGES * EDIMC, WT + (size_t)(25 + mp) * 16384);
      } else {
        proj<128, 3, false><<<gN, 256, 0, stream>>>(
            fchi, nullptr, base, KVn, KVn + 128, Qn, 256, 256, 128, N_NODES);
        edge_fused<0><<<gE, 512, 0, stream>>>(
            ehi, base + (size_t)3 * 16384, KVn, adj + (size_t)mp * E_EDGES * 2, KVe,
            nullptr, nullptr);
      }
      node_attn<<<N_NODES / 4, 256, 0, stream>>>(
          (const unsigned int*)Qn, (const unsigned int*)KVe,
          n2e + (size_t)mp * N_NODES * S_NEI, fnhi,
          out + (size_t)mp * N_NODES * 256 + (size_t)l * 128);

      fchi = fnhi; fnhi = fb;
    }
  }
}